// Round 5
// baseline (9290.137 us; speedup 1.0000x reference)
//
#include <hip/hip_runtime.h>
#include <hip/hip_bf16.h>

#define NSEQ 512
#define WD   256
#define LD   256
#define NG   1024      // 4*LD gates
#define FEAT 512
#define HID  512
#define NREL 100

typedef _Float16 h2_t __attribute__((ext_vector_type(2)));

__device__ __forceinline__ float fsig(float x) {
    x = fminf(fmaxf(x, -30.f), 30.f);
    return 1.f / (1.f + __expf(-x));
}
__device__ __forceinline__ float ftanh(float x) {
    x = fminf(fmaxf(x, -15.f), 15.f);
    float e = __expf(2.f * x);
    return (e - 1.f) / (e + 1.f);
}

// agent-scope (Infinity Cache) relaxed ops: sc0 sc1, no cache maintenance
__device__ __forceinline__ void st_ic_u32(unsigned* p, unsigned v) {
    __hip_atomic_store(p, v, __ATOMIC_RELAXED, __HIP_MEMORY_SCOPE_AGENT);
}
__device__ __forceinline__ unsigned long long ld_ic_u64(const unsigned long long* p) {
    return __hip_atomic_load((unsigned long long*)p, __ATOMIC_RELAXED,
                             __HIP_MEMORY_SCOPE_AGENT);
}

__device__ __forceinline__ float fdot2_acc(unsigned a, unsigned b, float c) {
#if __has_builtin(__builtin_amdgcn_fdot2)
    return __builtin_amdgcn_fdot2(__builtin_bit_cast(h2_t, a),
                                  __builtin_bit_cast(h2_t, b), c, false);
#else
    h2_t ha = __builtin_bit_cast(h2_t, a), hb = __builtin_bit_cast(h2_t, b);
    c = fmaf((float)ha.x, (float)hb.x, c);
    return fmaf((float)ha.y, (float)hb.y, c);
#endif
}

// ---------------- embedding gather ----------------
__global__ void embed_kernel(const int* __restrict__ tok, const float* __restrict__ E,
                             float* __restrict__ x) {
    int b = blockIdx.x;
    int t = tok[b];
    x[b * WD + threadIdx.x] = E[(long long)t * WD + threadIdx.x];
}

// ---------------- generic tiled GEMM: C = A(MxK) @ W(KxN) + bias ----------------
__global__ __launch_bounds__(256) void gemm_bias_kernel(
        const float* __restrict__ A, const float* __restrict__ W,
        const float* __restrict__ bias, float* __restrict__ C,
        int M, int K, int N) {
    __shared__ float As[16][65];
    alignas(16) __shared__ float Ws[16][68];
    int tid = threadIdx.x;
    int m0 = blockIdx.y * 64, n0 = blockIdx.x * 64;
    int tx = tid & 15, ty = tid >> 4;
    float acc[4][4] = {};
    int am = tid >> 2, akq = (tid & 3) * 4;
    int wk = tid >> 4, wn = (tid & 15) * 4;
    for (int k0 = 0; k0 < K; k0 += 16) {
        float4 av = *(const float4*)&A[(m0 + am) * K + k0 + akq];
        As[akq + 0][am] = av.x; As[akq + 1][am] = av.y;
        As[akq + 2][am] = av.z; As[akq + 3][am] = av.w;
        float4 wv = *(const float4*)&W[(k0 + wk) * N + n0 + wn];
        *(float4*)&Ws[wk][wn] = wv;
        __syncthreads();
        #pragma unroll
        for (int kk = 0; kk < 16; ++kk) {
            float a[4], w[4];
            #pragma unroll
            for (int q = 0; q < 4; ++q) { a[q] = As[kk][ty * 4 + q]; w[q] = Ws[kk][tx * 4 + q]; }
            #pragma unroll
            for (int i = 0; i < 4; ++i)
                #pragma unroll
                for (int j = 0; j < 4; ++j) acc[i][j] = fmaf(a[i], w[j], acc[i][j]);
        }
        __syncthreads();
    }
    #pragma unroll
    for (int i = 0; i < 4; ++i) {
        int row = m0 + ty * 4 + i;
        #pragma unroll
        for (int j = 0; j < 4; ++j) {
            int colx = n0 + tx * 4 + j;
            float b = bias ? bias[colx] : 0.f;
            C[row * N + colx] = acc[i][j] + b;
        }
    }
}

// ---------------- bidirectional LSTM layer ----------------
// 4 blocks x 1024 threads. block = (dir, half); each owns 128 h-outputs
// (512 gate cols). Weights f16x2-packed, register-resident (32 VGPRs).
// Per-step exchange of the OTHER half's 128 h via IC: one tagged u32 per h
// (tag = step in low 8 mantissa bits; single-dword store = untearable),
// parity-slot double-buffered, relaxed agent-scope ops only. The polling
// wave (15) fetches step s+1's data concurrently with the activation waves'
// z/act/store tail. Deadlock-free by induction on steps (round-3 protocol).
__global__ __launch_bounds__(1024) void lstm_kernel(
        const float* __restrict__ Xf, const float* __restrict__ Xb,
        const float* __restrict__ WhF, const float* __restrict__ WhB,
        float* __restrict__ H, unsigned* __restrict__ stage) {
    int tid = threadIdx.x;
    int dir = blockIdx.x >> 1, half = blockIdx.x & 1;
    const float* X  = dir ? Xb : Xf;
    const float* Wh = dir ? WhB : WhF;
    unsigned* stg = stage + dir * 512;     // [2 slots][256] tagged u32
    int ksl = tid >> 9;                    // k-slice 0..1 (128 k each)
    int cl  = tid & 511;                   // col-local 0..511
    int gt = cl >> 7, jj = cl & 127;
    int col = gt * 256 + half * 128 + jj;  // global gate column in [0,1024)
    int wid = tid >> 6, lane = tid & 63;

    unsigned w2[64];                       // 128 f16 weights packed
    #pragma unroll 8
    for (int m = 0; m < 64; ++m) {
        float a = Wh[(ksl * 128 + 2 * m) * NG + col];
        float b = Wh[(ksl * 128 + 2 * m + 1) * NG + col];
        w2[m] = __builtin_bit_cast(unsigned, __builtin_amdgcn_cvt_pkrtz(a, b));
    }

    alignas(16) __shared__ unsigned hpk[128];   // all 256 h as f16 pairs
    __shared__ float partial[2][520];
    if (tid < 128) hpk[tid] = 0u;
    float c_reg = 0.f;
    __syncthreads();

    const uint4* hp4 = (const uint4*)&hpk[ksl * 64];
    _Float16* hp16 = (_Float16*)hpk;

    for (int s = 0; s < NSEQ; ++s) {
        int t = dir ? (NSEQ - 1 - s) : s;
        // prefetch x-gates (consumed after the dot barrier)
        float xg4[4];
        if (tid < 128) {
            #pragma unroll
            for (int g = 0; g < 4; ++g)
                xg4[g] = X[t * NG + g * 256 + half * 128 + tid];
        }
        // dot over this k-slice: 64 fdot2 (128 MACs), f32 accumulate
        float a0 = 0.f, a1 = 0.f;
        #pragma unroll
        for (int m = 0; m < 16; ++m) {
            uint4 hp = hp4[m];
            a0 = fdot2_acc(w2[m * 4 + 0], hp.x, a0);
            a1 = fdot2_acc(w2[m * 4 + 1], hp.y, a1);
            a0 = fdot2_acc(w2[m * 4 + 2], hp.z, a0);
            a1 = fdot2_acc(w2[m * 4 + 3], hp.w, a1);
        }
        partial[ksl][cl] = a0 + a1;
        __syncthreads();                       // barrier 2: partial ready
        if (tid < 128) {
            float z[4];
            #pragma unroll
            for (int g = 0; g < 4; ++g)
                z[g] = xg4[g] + partial[0][g * 128 + tid] + partial[1][g * 128 + tid];
            c_reg = fsig(z[1]) * c_reg + fsig(z[0]) * ftanh(z[2]);
            float h = fsig(z[3]) * ftanh(c_reg);
            // latency-critical IC store first (tag s+1, parity slot s&1)
            unsigned pk = (__float_as_uint(h) & 0xFFFFFF00u) | ((unsigned)(s + 1) & 0xFFu);
            st_ic_u32(&stg[(s & 1) * 256 + half * 128 + tid], pk);
            hp16[half * 128 + tid] = (_Float16)h;   // own half, f16 in LDS
            H[t * FEAT + dir * LD + half * 128 + tid] = h;
        }
        // wave 15 polls the remote half for step s+1, overlapped with act
        if (wid == 15 && s + 1 < NSEQ) {
            int ridx = (1 - half) * 128 + 2 * lane;
            const unsigned long long* src =
                (const unsigned long long*)&stg[(s & 1) * 256 + ridx];
            unsigned want = (unsigned)(s + 1) & 0xFFu;
            unsigned long long pk;
            bool ok;
            do {
                pk = ld_ic_u64(src);
                ok = (((unsigned)pk & 0xFFu) == want) &&
                     (((unsigned)(pk >> 32) & 0xFFu) == want);
            } while (__any(!ok));
            float h0 = __uint_as_float((unsigned)pk & 0xFFFFFF00u);
            float h1 = __uint_as_float((unsigned)(pk >> 32) & 0xFFFFFF00u);
            hpk[(1 - half) * 64 + lane] =
                __builtin_bit_cast(unsigned, __builtin_amdgcn_cvt_pkrtz(h0, h1));
        }
        __syncthreads();                       // barrier 1: hpk ready for s+1
    }
}

// ---------------- arc scorer: out[i,j] = tanh(Hh[i]+Mh[j]) . outW + outB ----------------
__global__ __launch_bounds__(256) void arc_kernel(
        const float* __restrict__ Hh, const float* __restrict__ Mh,
        const float* __restrict__ outW, const float* __restrict__ outB,
        float* __restrict__ out) {
    __shared__ float Hs[16][513];
    __shared__ float Ms[16][513];
    __shared__ float wW[512];
    int tid = threadIdx.x;
    int i0 = blockIdx.y * 16, j0 = blockIdx.x * 16;
    int r = tid >> 4, kb = (tid & 15) * 4;
    #pragma unroll
    for (int q = 0; q < 8; ++q) {
        int k = kb + q * 64;
        float4 hv = *(const float4*)&Hh[(i0 + r) * HID + k];
        Hs[r][k] = hv.x; Hs[r][k + 1] = hv.y; Hs[r][k + 2] = hv.z; Hs[r][k + 3] = hv.w;
        float4 mv = *(const float4*)&Mh[(j0 + r) * HID + k];
        Ms[r][k] = mv.x; Ms[r][k + 1] = mv.y; Ms[r][k + 2] = mv.z; Ms[r][k + 3] = mv.w;
    }
    wW[tid] = outW[tid];
    wW[tid + 256] = outW[tid + 256];
    __syncthreads();
    int ti = tid >> 4, tj = tid & 15;
    float acc = 0.f;
    #pragma unroll 4
    for (int k = 0; k < 512; ++k)
        acc += ftanh(Hs[ti][k] + Ms[tj][k]) * wW[k];
    out[(i0 + ti) * NSEQ + (j0 + tj)] = acc + outB[0];
}

// ---------------- relation scorer ----------------
__global__ __launch_bounds__(256) void rel_kernel(
        const float* __restrict__ Rh, const float* __restrict__ Rm,
        const float* __restrict__ routW, const float* __restrict__ routB,
        float* __restrict__ out) {
    alignas(16) __shared__ float act_t[64][68];
    alignas(16) __shared__ float rw[64 * 100];
    __shared__ float rh_s[64];
    int tid = threadIdx.x;
    int i = blockIdx.x >> 3;
    int j0 = (blockIdx.x & 7) * 64;
    int rt = tid % 25, pg = tid / 25;   // valid when tid<200
    bool active = tid < 200;
    float acc[8][4] = {};
    int p = tid & 63, ksl = tid >> 6;
    for (int c = 0; c < 8; ++c) {
        int k0 = c * 64;
        #pragma unroll
        for (int q = 0; q < 25; ++q)
            rw[q * 256 + tid] = routW[k0 * 100 + q * 256 + tid];
        if (tid < 64) rh_s[tid] = Rh[i * HID + k0 + tid];
        __syncthreads();
        #pragma unroll
        for (int kk4 = 0; kk4 < 4; ++kk4) {
            int k = ksl * 16 + kk4 * 4;
            float4 mv = *(const float4*)&Rm[(j0 + p) * HID + k0 + k];
            act_t[k + 0][p] = ftanh(rh_s[k + 0] + mv.x);
            act_t[k + 1][p] = ftanh(rh_s[k + 1] + mv.y);
            act_t[k + 2][p] = ftanh(rh_s[k + 2] + mv.z);
            act_t[k + 3][p] = ftanh(rh_s[k + 3] + mv.w);
        }
        __syncthreads();
        if (active) {
            #pragma unroll 4
            for (int k = 0; k < 64; ++k) {
                float4 a0 = *(const float4*)&act_t[k][pg * 8];
                float4 a1 = *(const float4*)&act_t[k][pg * 8 + 4];
                float4 wv = *(const float4*)&rw[k * 100 + rt * 4];
                float av[8] = {a0.x, a0.y, a0.z, a0.w, a1.x, a1.y, a1.z, a1.w};
                float wf[4] = {wv.x, wv.y, wv.z, wv.w};
                #pragma unroll
                for (int pp = 0; pp < 8; ++pp)
                    #pragma unroll
                    for (int rr = 0; rr < 4; ++rr)
                        acc[pp][rr] = fmaf(av[pp], wf[rr], acc[pp][rr]);
            }
        }
        __syncthreads();
    }
    if (active) {
        #pragma unroll
        for (int pp = 0; pp < 8; ++pp) {
            int j = j0 + pg * 8 + pp;
            #pragma unroll
            for (int rr = 0; rr < 4; ++rr) {
                int rg = rt * 4 + rr;
                out[(long long)(i * NSEQ + j) * NREL + rg] = acc[pp][rr] + routB[rg];
            }
        }
    }
}

extern "C" void kernel_launch(void* const* d_in, const int* in_sizes, int n_in,
                              void* d_out, int out_size, void* d_ws, size_t ws_size,
                              hipStream_t stream) {
    const int*   tokens = (const int*)d_in[0];
    const float* E      = (const float*)d_in[1];
    const float* Wx_f1  = (const float*)d_in[2];
    const float* Wh_f1  = (const float*)d_in[3];
    const float* b_f1   = (const float*)d_in[4];
    const float* Wx_b1  = (const float*)d_in[5];
    const float* Wh_b1  = (const float*)d_in[6];
    const float* b_b1   = (const float*)d_in[7];
    const float* Wx_f2  = (const float*)d_in[8];
    const float* Wh_f2  = (const float*)d_in[9];
    const float* b_f2   = (const float*)d_in[10];
    const float* Wx_b2  = (const float*)d_in[11];
    const float* Wh_b2  = (const float*)d_in[12];
    const float* b_b2   = (const float*)d_in[13];
    const float* hidFOH = (const float*)d_in[14];
    const float* hidFOM = (const float*)d_in[15];
    const float* hidBias= (const float*)d_in[16];
    const float* outW   = (const float*)d_in[17];
    const float* outB   = (const float*)d_in[18];
    const float* rhidFOH= (const float*)d_in[19];
    const float* rhidFOM= (const float*)d_in[20];
    const float* rhidBias=(const float*)d_in[21];
    const float* routW  = (const float*)d_in[22];
    const float* routB  = (const float*)d_in[23];

    float* ws  = (float*)d_ws;
    float* x   = ws;                  // 512*256
    float* Xf1 = x + 131072;          // 512*1024
    float* Xb1 = Xf1 + 524288;
    float* h1  = Xb1 + 524288;        // 512*512
    float* Xf2 = h1 + 262144;
    float* Xb2 = Xf2 + 524288;
    float* h2  = Xb2 + 524288;        // 512*512
    float* Hh  = h2 + 262144;
    float* Mh  = Hh + 262144;
    float* Rh  = Mh + 262144;
    float* Rm  = Rh + 262144;
    // stage: 2 layers x (2 dirs x 2 slots x 256) tagged u32
    unsigned* stage1 = (unsigned*)(Rm + 262144);
    unsigned* stage2 = stage1 + 1024;

    float* arc_out = (float*)d_out;
    float* rel_out = arc_out + NSEQ * NSEQ;

    hipMemsetAsync(stage1, 0, 2048 * sizeof(unsigned), stream);
    embed_kernel<<<NSEQ, WD, 0, stream>>>(tokens, E, x);
    dim3 g1(NG / 64, NSEQ / 64);
    gemm_bias_kernel<<<g1, 256, 0, stream>>>(x, Wx_f1, b_f1, Xf1, NSEQ, WD, NG);
    gemm_bias_kernel<<<g1, 256, 0, stream>>>(x, Wx_b1, b_b1, Xb1, NSEQ, WD, NG);
    lstm_kernel<<<4, 1024, 0, stream>>>(Xf1, Xb1, Wh_f1, Wh_b1, h1, stage1);
    gemm_bias_kernel<<<g1, 256, 0, stream>>>(h1, Wx_f2, b_f2, Xf2, NSEQ, FEAT, NG);
    gemm_bias_kernel<<<g1, 256, 0, stream>>>(h1, Wx_b2, b_b2, Xb2, NSEQ, FEAT, NG);
    lstm_kernel<<<4, 1024, 0, stream>>>(Xf2, Xb2, Wh_f2, Wh_b2, h2, stage2);
    dim3 g2(HID / 64, NSEQ / 64);
    gemm_bias_kernel<<<g2, 256, 0, stream>>>(h2, hidFOH, hidBias, Hh, NSEQ, FEAT, HID);
    gemm_bias_kernel<<<g2, 256, 0, stream>>>(h2, hidFOM, nullptr, Mh, NSEQ, FEAT, HID);
    gemm_bias_kernel<<<g2, 256, 0, stream>>>(h2, rhidFOH, rhidBias, Rh, NSEQ, FEAT, HID);
    gemm_bias_kernel<<<g2, 256, 0, stream>>>(h2, rhidFOM, nullptr, Rm, NSEQ, FEAT, HID);
    dim3 ga(NSEQ / 16, NSEQ / 16);
    arc_kernel<<<ga, 256, 0, stream>>>(Hh, Mh, outW, outB, arc_out);
    rel_kernel<<<NSEQ * 8, 256, 0, stream>>>(Rh, Rm, routW, routB, rel_out);
}

// Round 6
// 2288.998 us; speedup vs baseline: 4.0586x; 4.0586x over previous
//
#include <hip/hip_runtime.h>
#include <hip/hip_bf16.h>

#define NSEQ 512
#define WD   256
#define LD   256
#define NG   1024      // 4*LD gates
#define FEAT 512
#define HID  512
#define NREL 100

typedef _Float16 h2_t __attribute__((ext_vector_type(2)));

__device__ __forceinline__ float fsig(float x) {
    x = fminf(fmaxf(x, -30.f), 30.f);
    return 1.f / (1.f + __expf(-x));
}
__device__ __forceinline__ float ftanh(float x) {
    x = fminf(fmaxf(x, -15.f), 15.f);
    float e = __expf(2.f * x);
    return (e - 1.f) / (e + 1.f);
}

__device__ __forceinline__ float fdot2_acc(unsigned a, unsigned b, float c) {
#if __has_builtin(__builtin_amdgcn_fdot2)
    return __builtin_amdgcn_fdot2(__builtin_bit_cast(h2_t, a),
                                  __builtin_bit_cast(h2_t, b), c, false);
#else
    h2_t ha = __builtin_bit_cast(h2_t, a), hb = __builtin_bit_cast(h2_t, b);
    c = fmaf((float)ha.x, (float)hb.x, c);
    return fmaf((float)ha.y, (float)hb.y, c);
#endif
}

// ---------------- embedding gather ----------------
__global__ void embed_kernel(const int* __restrict__ tok, const float* __restrict__ E,
                             float* __restrict__ x) {
    int b = blockIdx.x;
    int t = tok[b];
    x[b * WD + threadIdx.x] = E[(long long)t * WD + threadIdx.x];
}

// ---------------- generic tiled GEMM: C = A(MxK) @ W(KxN) + bias ----------------
__global__ __launch_bounds__(256) void gemm_bias_kernel(
        const float* __restrict__ A, const float* __restrict__ W,
        const float* __restrict__ bias, float* __restrict__ C,
        int M, int K, int N) {
    __shared__ float As[16][65];
    alignas(16) __shared__ float Ws[16][68];
    int tid = threadIdx.x;
    int m0 = blockIdx.y * 64, n0 = blockIdx.x * 64;
    int tx = tid & 15, ty = tid >> 4;
    float acc[4][4] = {};
    int am = tid >> 2, akq = (tid & 3) * 4;
    int wk = tid >> 4, wn = (tid & 15) * 4;
    for (int k0 = 0; k0 < K; k0 += 16) {
        float4 av = *(const float4*)&A[(m0 + am) * K + k0 + akq];
        As[akq + 0][am] = av.x; As[akq + 1][am] = av.y;
        As[akq + 2][am] = av.z; As[akq + 3][am] = av.w;
        float4 wv = *(const float4*)&W[(k0 + wk) * N + n0 + wn];
        *(float4*)&Ws[wk][wn] = wv;
        __syncthreads();
        #pragma unroll
        for (int kk = 0; kk < 16; ++kk) {
            float a[4], w[4];
            #pragma unroll
            for (int q = 0; q < 4; ++q) { a[q] = As[kk][ty * 4 + q]; w[q] = Ws[kk][tx * 4 + q]; }
            #pragma unroll
            for (int i = 0; i < 4; ++i)
                #pragma unroll
                for (int j = 0; j < 4; ++j) acc[i][j] = fmaf(a[i], w[j], acc[i][j]);
        }
        __syncthreads();
    }
    #pragma unroll
    for (int i = 0; i < 4; ++i) {
        int row = m0 + ty * 4 + i;
        #pragma unroll
        for (int j = 0; j < 4; ++j) {
            int colx = n0 + tx * 4 + j;
            float b = bias ? bias[colx] : 0.f;
            C[row * N + colx] = acc[i][j] + b;
        }
    }
}

// ---------------- bidirectional LSTM layer ----------------
// Round-3 protocol (proven): 8 blocks, blocks 0-3 forward / 4-7 backward,
// block owns 64 h. Exchange via IC: u64 (tag32|f32 value) per h element,
// parity-slot double-buffered, relaxed agent-scope ops, per-thread poll.
// New: 512 threads (__launch_bounds__(512,2) -> no spill), f16x2 weights in
// 64 VGPRs + v_dot2_f32_f16 (2 k-slices of 128), and pollers (waves 4-7)
// fetch step s+1's remote chunks OVERLAPPED with wave 0's activation tail.
__global__ __launch_bounds__(512, 2) void lstm_kernel(
        const float* __restrict__ Xf, const float* __restrict__ Xb,
        const float* __restrict__ WhF, const float* __restrict__ WhB,
        float* __restrict__ H, unsigned long long* __restrict__ stage) {
    int tid = threadIdx.x;
    int dir = blockIdx.x >> 2, blk = blockIdx.x & 3;
    const float* X  = dir ? Xb : Xf;
    const float* Wh = dir ? WhB : WhF;
    unsigned long long* stg = stage + dir * 512;   // [2 slots][256] u64
    int cl  = tid & 255;                 // col-local: gate g = cl>>6, jj = cl&63
    int ksl = tid >> 8;                  // k-slice 0..1 (128 k each)
    int col = (cl >> 6) * 256 + blk * 64 + (cl & 63);   // global gate column
    int lane = tid & 63;

    // 128 f16 weights packed into 64 VGPRs; fully unrolled, static indexing
    unsigned w2[64];
    #pragma unroll
    for (int m = 0; m < 64; ++m) {
        float a = Wh[(ksl * 128 + 2 * m) * NG + col];
        float b = Wh[(ksl * 128 + 2 * m + 1) * NG + col];
        w2[m] = __builtin_bit_cast(unsigned, __builtin_amdgcn_cvt_pkrtz(a, b));
    }

    alignas(16) __shared__ unsigned hpk[128];   // 256 h as f16 pairs
    __shared__ float partial[2][256];
    if (tid < 128) hpk[tid] = 0u;
    float c_reg = 0.f;
    __syncthreads();

    _Float16* hp16 = (_Float16*)hpk;

    for (int s = 0; s < NSEQ; ++s) {
        int t = dir ? (NSEQ - 1 - s) : s;
        // prefetch x-gates (wave 0 only; consumed after the dot barrier)
        float xg4[4];
        if (tid < 64) {
            #pragma unroll
            for (int g = 0; g < 4; ++g)
                xg4[g] = X[t * NG + g * 256 + blk * 64 + lane];
        }
        // dot over this k-slice: 64 fdot2 (128 MACs), h broadcast from LDS
        const uint4* hp4 = (const uint4*)&hpk[ksl * 64];
        float a0 = 0.f, a1 = 0.f;
        #pragma unroll
        for (int m = 0; m < 16; ++m) {
            uint4 hp = hp4[m];
            a0 = fdot2_acc(w2[m * 4 + 0], hp.x, a0);
            a1 = fdot2_acc(w2[m * 4 + 1], hp.y, a1);
            a0 = fdot2_acc(w2[m * 4 + 2], hp.z, a0);
            a1 = fdot2_acc(w2[m * 4 + 3], hp.w, a1);
        }
        partial[ksl][cl] = a0 + a1;
        __syncthreads();
        if (tid < 64) {
            // activation + latency-critical IC store
            float z[4];
            #pragma unroll
            for (int g = 0; g < 4; ++g)
                z[g] = xg4[g] + partial[0][g * 64 + lane] + partial[1][g * 64 + lane];
            c_reg = fsig(z[1]) * c_reg + fsig(z[0]) * ftanh(z[2]);
            float h = fsig(z[3]) * ftanh(c_reg);
            unsigned long long pk = ((unsigned long long)(unsigned)(s + 1) << 32)
                                  | (unsigned long long)__float_as_uint(h);
            __hip_atomic_store(&stg[(s & 1) * 256 + blk * 64 + lane], pk,
                               __ATOMIC_RELAXED, __HIP_MEMORY_SCOPE_AGENT);
            hp16[blk * 64 + lane] = (_Float16)h;        // own chunk via LDS
            H[t * FEAT + dir * LD + blk * 64 + lane] = h;
        } else if (tid >= 256 && s + 1 < NSEQ) {
            // pollers: fetch remote chunks for step s+1, overlapped with act
            int pidx = tid & 255;
            if ((pidx >> 6) != blk) {
                const unsigned long long* src = &stg[(s & 1) * 256 + pidx];
                unsigned long long pk;
                do {
                    pk = __hip_atomic_load((unsigned long long*)src,
                                           __ATOMIC_RELAXED, __HIP_MEMORY_SCOPE_AGENT);
                } while ((unsigned)(pk >> 32) != (unsigned)(s + 1));
                hp16[pidx] = (_Float16)__uint_as_float((unsigned)(pk & 0xffffffffu));
            }
        }
        __syncthreads();
    }
}

// ---------------- arc scorer: out[i,j] = tanh(Hh[i]+Mh[j]) . outW + outB ----------------
__global__ __launch_bounds__(256) void arc_kernel(
        const float* __restrict__ Hh, const float* __restrict__ Mh,
        const float* __restrict__ outW, const float* __restrict__ outB,
        float* __restrict__ out) {
    __shared__ float Hs[16][513];
    __shared__ float Ms[16][513];
    __shared__ float wW[512];
    int tid = threadIdx.x;
    int i0 = blockIdx.y * 16, j0 = blockIdx.x * 16;
    int r = tid >> 4, kb = (tid & 15) * 4;
    #pragma unroll
    for (int q = 0; q < 8; ++q) {
        int k = kb + q * 64;
        float4 hv = *(const float4*)&Hh[(i0 + r) * HID + k];
        Hs[r][k] = hv.x; Hs[r][k + 1] = hv.y; Hs[r][k + 2] = hv.z; Hs[r][k + 3] = hv.w;
        float4 mv = *(const float4*)&Mh[(j0 + r) * HID + k];
        Ms[r][k] = mv.x; Ms[r][k + 1] = mv.y; Ms[r][k + 2] = mv.z; Ms[r][k + 3] = mv.w;
    }
    wW[tid] = outW[tid];
    wW[tid + 256] = outW[tid + 256];
    __syncthreads();
    int ti = tid >> 4, tj = tid & 15;
    float acc = 0.f;
    #pragma unroll 4
    for (int k = 0; k < 512; ++k)
        acc += ftanh(Hs[ti][k] + Ms[tj][k]) * wW[k];
    out[(i0 + ti) * NSEQ + (j0 + tj)] = acc + outB[0];
}

// ---------------- relation scorer ----------------
__global__ __launch_bounds__(256) void rel_kernel(
        const float* __restrict__ Rh, const float* __restrict__ Rm,
        const float* __restrict__ routW, const float* __restrict__ routB,
        float* __restrict__ out) {
    alignas(16) __shared__ float act_t[64][68];
    alignas(16) __shared__ float rw[64 * 100];
    __shared__ float rh_s[64];
    int tid = threadIdx.x;
    int i = blockIdx.x >> 3;
    int j0 = (blockIdx.x & 7) * 64;
    int rt = tid % 25, pg = tid / 25;   // valid when tid<200
    bool active = tid < 200;
    float acc[8][4] = {};
    int p = tid & 63, ksl = tid >> 6;
    for (int c = 0; c < 8; ++c) {
        int k0 = c * 64;
        #pragma unroll
        for (int q = 0; q < 25; ++q)
            rw[q * 256 + tid] = routW[k0 * 100 + q * 256 + tid];
        if (tid < 64) rh_s[tid] = Rh[i * HID + k0 + tid];
        __syncthreads();
        #pragma unroll
        for (int kk4 = 0; kk4 < 4; ++kk4) {
            int k = ksl * 16 + kk4 * 4;
            float4 mv = *(const float4*)&Rm[(j0 + p) * HID + k0 + k];
            act_t[k + 0][p] = ftanh(rh_s[k + 0] + mv.x);
            act_t[k + 1][p] = ftanh(rh_s[k + 1] + mv.y);
            act_t[k + 2][p] = ftanh(rh_s[k + 2] + mv.z);
            act_t[k + 3][p] = ftanh(rh_s[k + 3] + mv.w);
        }
        __syncthreads();
        if (active) {
            #pragma unroll 4
            for (int k = 0; k < 64; ++k) {
                float4 a0 = *(const float4*)&act_t[k][pg * 8];
                float4 a1 = *(const float4*)&act_t[k][pg * 8 + 4];
                float4 wv = *(const float4*)&rw[k * 100 + rt * 4];
                float av[8] = {a0.x, a0.y, a0.z, a0.w, a1.x, a1.y, a1.z, a1.w};
                float wf[4] = {wv.x, wv.y, wv.z, wv.w};
                #pragma unroll
                for (int pp = 0; pp < 8; ++pp)
                    #pragma unroll
                    for (int rr = 0; rr < 4; ++rr)
                        acc[pp][rr] = fmaf(av[pp], wf[rr], acc[pp][rr]);
            }
        }
        __syncthreads();
    }
    if (active) {
        #pragma unroll
        for (int pp = 0; pp < 8; ++pp) {
            int j = j0 + pg * 8 + pp;
            #pragma unroll
            for (int rr = 0; rr < 4; ++rr) {
                int rg = rt * 4 + rr;
                out[(long long)(i * NSEQ + j) * NREL + rg] = acc[pp][rr] + routB[rg];
            }
        }
    }
}

extern "C" void kernel_launch(void* const* d_in, const int* in_sizes, int n_in,
                              void* d_out, int out_size, void* d_ws, size_t ws_size,
                              hipStream_t stream) {
    const int*   tokens = (const int*)d_in[0];
    const float* E      = (const float*)d_in[1];
    const float* Wx_f1  = (const float*)d_in[2];
    const float* Wh_f1  = (const float*)d_in[3];
    const float* b_f1   = (const float*)d_in[4];
    const float* Wx_b1  = (const float*)d_in[5];
    const float* Wh_b1  = (const float*)d_in[6];
    const float* b_b1   = (const float*)d_in[7];
    const float* Wx_f2  = (const float*)d_in[8];
    const float* Wh_f2  = (const float*)d_in[9];
    const float* b_f2   = (const float*)d_in[10];
    const float* Wx_b2  = (const float*)d_in[11];
    const float* Wh_b2  = (const float*)d_in[12];
    const float* b_b2   = (const float*)d_in[13];
    const float* hidFOH = (const float*)d_in[14];
    const float* hidFOM = (const float*)d_in[15];
    const float* hidBias= (const float*)d_in[16];
    const float* outW   = (const float*)d_in[17];
    const float* outB   = (const float*)d_in[18];
    const float* rhidFOH= (const float*)d_in[19];
    const float* rhidFOM= (const float*)d_in[20];
    const float* rhidBias=(const float*)d_in[21];
    const float* routW  = (const float*)d_in[22];
    const float* routB  = (const float*)d_in[23];

    float* ws  = (float*)d_ws;
    float* x   = ws;                  // 512*256
    float* Xf1 = x + 131072;          // 512*1024
    float* Xb1 = Xf1 + 524288;
    float* h1  = Xb1 + 524288;        // 512*512
    float* Xf2 = h1 + 262144;
    float* Xb2 = Xf2 + 524288;
    float* h2  = Xb2 + 524288;        // 512*512
    float* Hh  = h2 + 262144;
    float* Mh  = Hh + 262144;
    float* Rh  = Mh + 262144;
    float* Rm  = Rh + 262144;
    // stage: 2 layers x (2 dirs x 2 slots x 256) u64
    unsigned long long* stage1 = (unsigned long long*)(Rm + 262144);
    unsigned long long* stage2 = stage1 + 1024;

    float* arc_out = (float*)d_out;
    float* rel_out = arc_out + NSEQ * NSEQ;

    hipMemsetAsync(stage1, 0, 2048 * sizeof(unsigned long long), stream);
    embed_kernel<<<NSEQ, WD, 0, stream>>>(tokens, E, x);
    dim3 g1(NG / 64, NSEQ / 64);
    gemm_bias_kernel<<<g1, 256, 0, stream>>>(x, Wx_f1, b_f1, Xf1, NSEQ, WD, NG);
    gemm_bias_kernel<<<g1, 256, 0, stream>>>(x, Wx_b1, b_b1, Xb1, NSEQ, WD, NG);
    lstm_kernel<<<8, 512, 0, stream>>>(Xf1, Xb1, Wh_f1, Wh_b1, h1, stage1);
    gemm_bias_kernel<<<g1, 256, 0, stream>>>(h1, Wx_f2, b_f2, Xf2, NSEQ, FEAT, NG);
    gemm_bias_kernel<<<g1, 256, 0, stream>>>(h1, Wx_b2, b_b2, Xb2, NSEQ, FEAT, NG);
    lstm_kernel<<<8, 512, 0, stream>>>(Xf2, Xb2, Wh_f2, Wh_b2, h2, stage2);
    dim3 g2(HID / 64, NSEQ / 64);
    gemm_bias_kernel<<<g2, 256, 0, stream>>>(h2, hidFOH, hidBias, Hh, NSEQ, FEAT, HID);
    gemm_bias_kernel<<<g2, 256, 0, stream>>>(h2, hidFOM, nullptr, Mh, NSEQ, FEAT, HID);
    gemm_bias_kernel<<<g2, 256, 0, stream>>>(h2, rhidFOH, rhidBias, Rh, NSEQ, FEAT, HID);
    gemm_bias_kernel<<<g2, 256, 0, stream>>>(h2, rhidFOM, nullptr, Rm, NSEQ, FEAT, HID);
    dim3 ga(NSEQ / 16, NSEQ / 16);
    arc_kernel<<<ga, 256, 0, stream>>>(Hh, Mh, outW, outB, arc_out);
    rel_kernel<<<NSEQ * 8, 256, 0, stream>>>(Rh, Rm, routW, routB, rel_out);
}

// Round 8
// 1923.018 us; speedup vs baseline: 4.8310x; 1.1903x over previous
//
#include <hip/hip_runtime.h>
#include <hip/hip_bf16.h>

#define NSEQ 512
#define WD   256
#define LD   256
#define NG   1024      // 4*LD gates
#define FEAT 512
#define HID  512
#define NREL 100

typedef _Float16 h2_t __attribute__((ext_vector_type(2)));
typedef _Float16 half8 __attribute__((ext_vector_type(8)));
typedef float f32x4 __attribute__((ext_vector_type(4)));

__device__ __forceinline__ float fsig(float x) {
    x = fminf(fmaxf(x, -30.f), 30.f);
    return 1.f / (1.f + __expf(-x));
}
__device__ __forceinline__ float ftanh(float x) {
    x = fminf(fmaxf(x, -15.f), 15.f);
    float e = __expf(2.f * x);
    return (e - 1.f) / (e + 1.f);
}

__device__ __forceinline__ float fdot2_acc(unsigned a, unsigned b, float c) {
#if __has_builtin(__builtin_amdgcn_fdot2)
    return __builtin_amdgcn_fdot2(__builtin_bit_cast(h2_t, a),
                                  __builtin_bit_cast(h2_t, b), c, false);
#else
    h2_t ha = __builtin_bit_cast(h2_t, a), hb = __builtin_bit_cast(h2_t, b);
    c = fmaf((float)ha.x, (float)hb.x, c);
    return fmaf((float)ha.y, (float)hb.y, c);
#endif
}
__device__ __forceinline__ unsigned pk16(float a, float b) {
    return __builtin_bit_cast(unsigned, __builtin_amdgcn_cvt_pkrtz(a, b));
}

// ---------------- embedding gather ----------------
__global__ void embed_kernel(const int* __restrict__ tok, const float* __restrict__ E,
                             float* __restrict__ x) {
    int b = blockIdx.x;
    int t = tok[b];
    x[b * WD + threadIdx.x] = E[(long long)t * WD + threadIdx.x];
}

// ---------------- routW -> f16 [n][k] (transposed, zero-padded to 112) ----------
__global__ void cvt_routw_kernel(const float* __restrict__ routW, _Float16* __restrict__ rw16) {
    int k = blockIdx.x;       // 512
    int n = threadIdx.x;      // 128 (guard)
    if (n < 112)
        rw16[n * 512 + k] = (n < NREL) ? (_Float16)routW[k * NREL + n] : (_Float16)0.f;
}

// ---------------- MFMA GEMM: C = A(MxK) @ W(KxN) + bias, f16 compute ----------------
// Tile 64x64, K-step 32, 256 threads (4 waves; wave w owns rows w*16..w*16+15).
// A [m][k] f16, B staged transposed [n][k] f16, mfma(a,b,acc);
// C/D: col=lane&15, row=(lane>>4)*4+reg.  (validated: arc output passed R7)
__global__ __launch_bounds__(256) void gemm_mfma_kernel(
        const float* __restrict__ A, const float* __restrict__ W,
        const float* __restrict__ bias, float* __restrict__ C,
        int M, int K, int N) {
    __shared__ _Float16 Ah[64][40];   // stride 80B (5x16B): b128-aligned rows
    __shared__ _Float16 Wt[64][40];
    int tid = threadIdx.x, wid = tid >> 6, l = tid & 63;
    int m0 = blockIdx.y * 64, n0 = blockIdx.x * 64;
    f32x4 acc[4] = {};
    int ar = tid >> 2, akq = (tid & 3) * 8;
    int wn = tid & 63, wkp0 = (tid >> 6) * 2;
    for (int k0 = 0; k0 < K; k0 += 32) {
        float4 a0 = *(const float4*)&A[(m0 + ar) * K + k0 + akq];
        float4 a1 = *(const float4*)&A[(m0 + ar) * K + k0 + akq + 4];
        uint4 ap = { pk16(a0.x, a0.y), pk16(a0.z, a0.w),
                     pk16(a1.x, a1.y), pk16(a1.z, a1.w) };
        *(uint4*)&Ah[ar][akq] = ap;
        #pragma unroll
        for (int it = 0; it < 4; ++it) {
            int kp = wkp0 + it * 8;
            float w0 = W[(k0 + kp) * N + n0 + wn];
            float w1 = W[(k0 + kp + 1) * N + n0 + wn];
            ((unsigned*)&Wt[wn][0])[kp >> 1] = pk16(w0, w1);
        }
        __syncthreads();
        half8 af = *(const half8*)&Ah[wid * 16 + (l & 15)][(l >> 4) * 8];
        #pragma unroll
        for (int nt = 0; nt < 4; ++nt) {
            half8 bf = *(const half8*)&Wt[nt * 16 + (l & 15)][(l >> 4) * 8];
            acc[nt] = __builtin_amdgcn_mfma_f32_16x16x32_f16(af, bf, acc[nt], 0, 0, 0);
        }
        __syncthreads();
    }
    int rbase = m0 + wid * 16 + (l >> 4) * 4;
    #pragma unroll
    for (int nt = 0; nt < 4; ++nt) {
        int col = n0 + nt * 16 + (l & 15);
        float b = bias ? bias[col] : 0.f;
        #pragma unroll
        for (int reg = 0; reg < 4; ++reg)
            C[(rbase + reg) * N + col] = acc[nt][reg] + b;
    }
}

// ---------------- bidirectional LSTM layer (unchanged, proven) ----------------
__global__ __launch_bounds__(512, 2) void lstm_kernel(
        const float* __restrict__ Xf, const float* __restrict__ Xb,
        const float* __restrict__ WhF, const float* __restrict__ WhB,
        float* __restrict__ H, unsigned long long* __restrict__ stage) {
    int tid = threadIdx.x;
    int dir = blockIdx.x >> 2, blk = blockIdx.x & 3;
    const float* X  = dir ? Xb : Xf;
    const float* Wh = dir ? WhB : WhF;
    unsigned long long* stg = stage + dir * 512;   // [2 slots][256] u64
    int cl  = tid & 255;
    int ksl = tid >> 8;
    int col = (cl >> 6) * 256 + blk * 64 + (cl & 63);
    int lane = tid & 63;

    unsigned w2[64];
    #pragma unroll
    for (int m = 0; m < 64; ++m) {
        float a = Wh[(ksl * 128 + 2 * m) * NG + col];
        float b = Wh[(ksl * 128 + 2 * m + 1) * NG + col];
        w2[m] = pk16(a, b);
    }

    alignas(16) __shared__ unsigned hpk[128];
    __shared__ float partial[2][256];
    if (tid < 128) hpk[tid] = 0u;
    float c_reg = 0.f;
    __syncthreads();

    _Float16* hp16 = (_Float16*)hpk;

    for (int s = 0; s < NSEQ; ++s) {
        int t = dir ? (NSEQ - 1 - s) : s;
        float xg4[4];
        if (tid < 64) {
            #pragma unroll
            for (int g = 0; g < 4; ++g)
                xg4[g] = X[t * NG + g * 256 + blk * 64 + lane];
        }
        const uint4* hp4 = (const uint4*)&hpk[ksl * 64];
        float a0 = 0.f, a1 = 0.f;
        #pragma unroll
        for (int m = 0; m < 16; ++m) {
            uint4 hp = hp4[m];
            a0 = fdot2_acc(w2[m * 4 + 0], hp.x, a0);
            a1 = fdot2_acc(w2[m * 4 + 1], hp.y, a1);
            a0 = fdot2_acc(w2[m * 4 + 2], hp.z, a0);
            a1 = fdot2_acc(w2[m * 4 + 3], hp.w, a1);
        }
        partial[ksl][cl] = a0 + a1;
        __syncthreads();
        if (tid < 64) {
            float z[4];
            #pragma unroll
            for (int g = 0; g < 4; ++g)
                z[g] = xg4[g] + partial[0][g * 64 + lane] + partial[1][g * 64 + lane];
            c_reg = fsig(z[1]) * c_reg + fsig(z[0]) * ftanh(z[2]);
            float h = fsig(z[3]) * ftanh(c_reg);
            unsigned long long pk = ((unsigned long long)(unsigned)(s + 1) << 32)
                                  | (unsigned long long)__float_as_uint(h);
            __hip_atomic_store(&stg[(s & 1) * 256 + blk * 64 + lane], pk,
                               __ATOMIC_RELAXED, __HIP_MEMORY_SCOPE_AGENT);
            hp16[blk * 64 + lane] = (_Float16)h;
            H[t * FEAT + dir * LD + blk * 64 + lane] = h;
        } else if (tid >= 256 && s + 1 < NSEQ) {
            int pidx = tid & 255;
            if ((pidx >> 6) != blk) {
                const unsigned long long* src = &stg[(s & 1) * 256 + pidx];
                unsigned long long pk;
                do {
                    pk = __hip_atomic_load((unsigned long long*)src,
                                           __ATOMIC_RELAXED, __HIP_MEMORY_SCOPE_AGENT);
                } while ((unsigned)(pk >> 32) != (unsigned)(s + 1));
                hp16[pidx] = (_Float16)__uint_as_float((unsigned)(pk & 0xffffffffu));
            }
        }
        __syncthreads();
    }
}

// ---------------- arc scorer (unchanged) ----------------
__global__ __launch_bounds__(256) void arc_kernel(
        const float* __restrict__ Hh, const float* __restrict__ Mh,
        const float* __restrict__ outW, const float* __restrict__ outB,
        float* __restrict__ out) {
    __shared__ float Hs[16][513];
    __shared__ float Ms[16][513];
    __shared__ float wW[512];
    int tid = threadIdx.x;
    int i0 = blockIdx.y * 16, j0 = blockIdx.x * 16;
    int r = tid >> 4, kb = (tid & 15) * 4;
    #pragma unroll
    for (int q = 0; q < 8; ++q) {
        int k = kb + q * 64;
        float4 hv = *(const float4*)&Hh[(i0 + r) * HID + k];
        Hs[r][k] = hv.x; Hs[r][k + 1] = hv.y; Hs[r][k + 2] = hv.z; Hs[r][k + 3] = hv.w;
        float4 mv = *(const float4*)&Mh[(j0 + r) * HID + k];
        Ms[r][k] = mv.x; Ms[r][k + 1] = mv.y; Ms[r][k + 2] = mv.z; Ms[r][k + 3] = mv.w;
    }
    wW[tid] = outW[tid];
    wW[tid + 256] = outW[tid + 256];
    __syncthreads();
    int ti = tid >> 4, tj = tid & 15;
    float acc = 0.f;
    #pragma unroll 4
    for (int k = 0; k < 512; ++k)
        acc += ftanh(Hs[ti][k] + Ms[tj][k]) * wW[k];
    out[(i0 + ti) * NSEQ + (j0 + tj)] = acc + outB[0];
}

// ---------------- relation scorer: MFMA f16 ----------------
// Block = (head i, 64 mods). 8 K-chunks of 64: compute act=tanh(Rh+Rm) into
// LDS f16 [j][k], stage routW f16 [n][k] chunk, then 4 waves x 7 n-tiles x
// 2 k MFMAs, acc f32. rw staging: 112 rows x 32 u32 = 3584 u32 = 14 reps
// of 256 threads (R7 bug: stride-512 left half the rows uninitialized).
__global__ __launch_bounds__(256) void rel_mfma_kernel(
        const float* __restrict__ Rh, const float* __restrict__ Rm,
        const _Float16* __restrict__ rw16, const float* __restrict__ routB,
        float* __restrict__ out) {
    __shared__ _Float16 act[64][72];    // stride 144B (9x16B)
    __shared__ _Float16 rw[112][72];
    __shared__ float rh_s[512];
    int tid = threadIdx.x, wid = tid >> 6, l = tid & 63;
    int i = blockIdx.x >> 3;
    int j0 = (blockIdx.x & 7) * 64;
    if (tid < 128)
        *(float4*)&rh_s[tid * 4] = *(const float4*)&Rh[i * HID + tid * 4];
    f32x4 acc[7] = {};
    int aj = tid >> 2, aks = (tid & 3) * 16;
    __syncthreads();

    for (int c = 0; c < 8; ++c) {
        int k0 = c * 64;
        // stage routW chunk [112][64] from rw16 [n][512]: full coverage
        #pragma unroll
        for (int rep = 0; rep < 14; ++rep) {
            int idx = rep * 256 + tid;
            int n = idx >> 5, ku = idx & 31;
            ((unsigned*)&rw[n][0])[ku] = *(const unsigned*)&rw16[n * 512 + k0 + ku * 2];
        }
        // act tile: 16 k per thread
        {
            const float* rmp = &Rm[(j0 + aj) * HID + k0 + aks];
            float4 r0 = *(const float4*)&rmp[0];
            float4 r1 = *(const float4*)&rmp[4];
            float4 r2 = *(const float4*)&rmp[8];
            float4 r3 = *(const float4*)&rmp[12];
            const float* rh = &rh_s[k0 + aks];
            float t0 = ftanh(rh[0]  + r0.x), t1 = ftanh(rh[1]  + r0.y);
            float t2 = ftanh(rh[2]  + r0.z), t3 = ftanh(rh[3]  + r0.w);
            float t4 = ftanh(rh[4]  + r1.x), t5 = ftanh(rh[5]  + r1.y);
            float t6 = ftanh(rh[6]  + r1.z), t7 = ftanh(rh[7]  + r1.w);
            uint4 p0 = { pk16(t0, t1), pk16(t2, t3), pk16(t4, t5), pk16(t6, t7) };
            *(uint4*)&act[aj][aks] = p0;
            float u0 = ftanh(rh[8]  + r2.x), u1 = ftanh(rh[9]  + r2.y);
            float u2 = ftanh(rh[10] + r2.z), u3 = ftanh(rh[11] + r2.w);
            float u4 = ftanh(rh[12] + r3.x), u5 = ftanh(rh[13] + r3.y);
            float u6 = ftanh(rh[14] + r3.z), u7 = ftanh(rh[15] + r3.w);
            uint4 p1 = { pk16(u0, u1), pk16(u2, u3), pk16(u4, u5), pk16(u6, u7) };
            *(uint4*)&act[aj][aks + 8] = p1;
        }
        __syncthreads();
        #pragma unroll
        for (int kk = 0; kk < 2; ++kk) {
            half8 af = *(const half8*)&act[wid * 16 + (l & 15)][kk * 32 + (l >> 4) * 8];
            #pragma unroll
            for (int nt = 0; nt < 7; ++nt) {
                half8 bf = *(const half8*)&rw[nt * 16 + (l & 15)][kk * 32 + (l >> 4) * 8];
                acc[nt] = __builtin_amdgcn_mfma_f32_16x16x32_f16(af, bf, acc[nt], 0, 0, 0);
            }
        }
        __syncthreads();
    }
    int jbase = j0 + wid * 16 + (l >> 4) * 4;
    #pragma unroll
    for (int nt = 0; nt < 7; ++nt) {
        int col = nt * 16 + (l & 15);
        if (col < NREL) {
            float b = routB[col];
            #pragma unroll
            for (int reg = 0; reg < 4; ++reg)
                out[(long long)(i * NSEQ + jbase + reg) * NREL + col] = acc[nt][reg] + b;
        }
    }
}

extern "C" void kernel_launch(void* const* d_in, const int* in_sizes, int n_in,
                              void* d_out, int out_size, void* d_ws, size_t ws_size,
                              hipStream_t stream) {
    const int*   tokens = (const int*)d_in[0];
    const float* E      = (const float*)d_in[1];
    const float* Wx_f1  = (const float*)d_in[2];
    const float* Wh_f1  = (const float*)d_in[3];
    const float* b_f1   = (const float*)d_in[4];
    const float* Wx_b1  = (const float*)d_in[5];
    const float* Wh_b1  = (const float*)d_in[6];
    const float* b_b1   = (const float*)d_in[7];
    const float* Wx_f2  = (const float*)d_in[8];
    const float* Wh_f2  = (const float*)d_in[9];
    const float* b_f2   = (const float*)d_in[10];
    const float* Wx_b2  = (const float*)d_in[11];
    const float* Wh_b2  = (const float*)d_in[12];
    const float* b_b2   = (const float*)d_in[13];
    const float* hidFOH = (const float*)d_in[14];
    const float* hidFOM = (const float*)d_in[15];
    const float* hidBias= (const float*)d_in[16];
    const float* outW   = (const float*)d_in[17];
    const float* outB   = (const float*)d_in[18];
    const float* rhidFOH= (const float*)d_in[19];
    const float* rhidFOM= (const float*)d_in[20];
    const float* rhidBias=(const float*)d_in[21];
    const float* routW  = (const float*)d_in[22];
    const float* routB  = (const float*)d_in[23];

    float* ws  = (float*)d_ws;
    float* x   = ws;                  // 512*256
    float* Xf1 = x + 131072;          // 512*1024
    float* Xb1 = Xf1 + 524288;
    float* h1  = Xb1 + 524288;        // 512*512
    float* Xf2 = h1 + 262144;
    float* Xb2 = Xf2 + 524288;
    float* h2  = Xb2 + 524288;        // 512*512
    float* Hh  = h2 + 262144;
    float* Mh  = Hh + 262144;
    float* Rh  = Mh + 262144;
    float* Rm  = Rh + 262144;
    unsigned long long* stage1 = (unsigned long long*)(Rm + 262144);
    unsigned long long* stage2 = stage1 + 1024;
    _Float16* rw16 = (_Float16*)(stage2 + 1024);   // 112 x 512 f16

    float* arc_out = (float*)d_out;
    float* rel_out = arc_out + NSEQ * NSEQ;

    hipMemsetAsync(stage1, 0, 2048 * sizeof(unsigned long long), stream);
    embed_kernel<<<NSEQ, WD, 0, stream>>>(tokens, E, x);
    cvt_routw_kernel<<<512, 128, 0, stream>>>(routW, rw16);
    dim3 g1(NG / 64, NSEQ / 64);
    gemm_mfma_kernel<<<g1, 256, 0, stream>>>(x, Wx_f1, b_f1, Xf1, NSEQ, WD, NG);
    gemm_mfma_kernel<<<g1, 256, 0, stream>>>(x, Wx_b1, b_b1, Xb1, NSEQ, WD, NG);
    lstm_kernel<<<8, 512, 0, stream>>>(Xf1, Xb1, Wh_f1, Wh_b1, h1, stage1);
    gemm_mfma_kernel<<<g1, 256, 0, stream>>>(h1, Wx_f2, b_f2, Xf2, NSEQ, FEAT, NG);
    gemm_mfma_kernel<<<g1, 256, 0, stream>>>(h1, Wx_b2, b_b2, Xb2, NSEQ, FEAT, NG);
    lstm_kernel<<<8, 512, 0, stream>>>(Xf2, Xb2, Wh_f2, Wh_b2, h2, stage2);
    dim3 g2(HID / 64, NSEQ / 64);
    gemm_mfma_kernel<<<g2, 256, 0, stream>>>(h2, hidFOH, hidBias, Hh, NSEQ, FEAT, HID);
    gemm_mfma_kernel<<<g2, 256, 0, stream>>>(h2, hidFOM, nullptr, Mh, NSEQ, FEAT, HID);
    gemm_mfma_kernel<<<g2, 256, 0, stream>>>(h2, rhidFOH, rhidBias, Rh, NSEQ, FEAT, HID);
    gemm_mfma_kernel<<<g2, 256, 0, stream>>>(h2, rhidFOM, nullptr, Rm, NSEQ, FEAT, HID);
    dim3 ga(NSEQ / 16, NSEQ / 16);
    arc_kernel<<<ga, 256, 0, stream>>>(Hh, Mh, outW, outB, arc_out);
    rel_mfma_kernel<<<NSEQ * 8, 256, 0, stream>>>(Rh, Rm, rw16, routB, rel_out);
}